// Round 11
// baseline (68.732 us; speedup 1.0000x reference)
//
#include <hip/hip_runtime.h>
#include <math.h>

#define TOK 12544   // B*H*W
#define CDIM 128
#define NHEAD 4
#define HD 32
#define KS 7
#define HSZ 56
#define WSZ 56

typedef __attribute__((ext_vector_type(8))) short short8;   // bf16x8 mfma frag
typedef __attribute__((ext_vector_type(4))) float f32x4;

__device__ inline ushort f2b(float f) {                      // fp32 -> bf16 RNE
    uint u = __float_as_uint(f);
    u += 0x7fffu + ((u >> 16) & 1u);
    return (ushort)(u >> 16);
}

// ---------- convert the 4 weight matrices to bf16 into one contiguous buffer ----------
__global__ void convert_w(const float* __restrict__ a, const float* __restrict__ b,
                          const float* __restrict__ c, const float* __restrict__ d,
                          ushort* __restrict__ wb) {
    int e = (blockIdx.x * 256 + threadIdx.x) * 4;
    const float* src;
    if (e < 49152)       src = a + e;
    else if (e < 65536)  src = b + (e - 49152);
    else if (e < 131072) src = c + (e - 65536);
    else                 src = d + (e - 131072);
    float4 v = *(const float4*)src;
    uint2 pk;
    pk.x = (uint)f2b(v.x) | ((uint)f2b(v.y) << 16);
    pk.y = (uint)f2b(v.z) | ((uint)f2b(v.w) << 16);
    *(uint2*)(wb + e) = pk;
}

// ---------- helper: LN of a 32-row tile into swizzled LDS (bf16), 4 waves ----------
__device__ inline void ln_to_lds32(const float* __restrict__ X, int m0,
                                   const float* __restrict__ lnw, const float* __restrict__ lnb,
                                   ushort* __restrict__ lds) {
    int wv = threadIdx.x >> 6, lane = threadIdx.x & 63;
    #pragma unroll
    for (int r = 0; r < 8; r++) {
        int rl = wv * 8 + r;
        float2 v = *(const float2*)(X + (size_t)(m0 + rl) * CDIM + lane * 2);
        float s = v.x + v.y;
        #pragma unroll
        for (int o = 32; o > 0; o >>= 1) s += __shfl_xor(s, o);
        float mu = s * (1.0f / 128.0f);
        float d0 = v.x - mu, d1 = v.y - mu;
        float sq = d0 * d0 + d1 * d1;
        #pragma unroll
        for (int o = 32; o > 0; o >>= 1) sq += __shfl_xor(sq, o);
        float rstd = rsqrtf(sq * (1.0f / 128.0f) + 1e-5f);
        float2 wv2 = *(const float2*)(lnw + lane * 2);
        float2 bv2 = *(const float2*)(lnb + lane * 2);
        uint pk = (uint)f2b(d0 * rstd * wv2.x + bv2.x)
                | ((uint)f2b(d1 * rstd * wv2.y + bv2.y) << 16);
        *(uint*)((char*)lds + rl * 256 + ((lane * 4) ^ ((rl & 7) << 4))) = pk;
    }
}

// ---------- fused LN1 + QKV GEMM: block = 32 rows x 384 cols, 256 thr (4 waves) ----------
// wave w owns cols [w*96, +96) (6 frags); per-wave MFMA = 4*2*6 = 48 (same as R10).
__global__ __launch_bounds__(256) void ln1_qkv(const float* __restrict__ X,
                                               const ushort* __restrict__ W,
                                               const float* __restrict__ bias,
                                               const float* __restrict__ lnw,
                                               const float* __restrict__ lnb,
                                               ushort* __restrict__ Y) {
    __shared__ ushort xn[32 * 128];   // 8 KB swizzled
    int m0 = blockIdx.x * 32;
    ln_to_lds32(X, m0, lnw, lnb, xn);
    __syncthreads();

    int wv = threadIdx.x >> 6, lane = threadIdx.x & 63;
    int lr = lane & 15, kg = lane >> 4;
    int n0 = wv * 96;
    f32x4 acc[2][6] = {};
    #pragma unroll
    for (int k0 = 0; k0 < 128; k0 += 32) {
        short8 bf[6];
        #pragma unroll
        for (int ni = 0; ni < 6; ni++)
            bf[ni] = *(const short8*)(W + (size_t)(n0 + ni * 16 + lr) * 128 + k0 + kg * 8);
        #pragma unroll
        for (int mg = 0; mg < 2; mg++) {
            int row = mg * 16 + lr;
            short8 a0 = *(const short8*)((char*)xn + row * 256 + ((k0 * 2 + kg * 16) ^ ((row & 7) << 4)));
            #pragma unroll
            for (int ni = 0; ni < 6; ni++)
                acc[mg][ni] = __builtin_amdgcn_mfma_f32_16x16x32_bf16(a0, bf[ni], acc[mg][ni], 0, 0, 0);
        }
    }
    #pragma unroll
    for (int mg = 0; mg < 2; mg++)
    #pragma unroll
    for (int ni = 0; ni < 6; ni++) {
        int col = n0 + ni * 16 + lr;
        float bn = bias[col];
        #pragma unroll
        for (int r = 0; r < 4; r++) {
            int row = m0 + mg * 16 + kg * 4 + r;
            float v = acc[mg][ni][r] + bn;
            if (col < CDIM) v *= 0.17677669529663687f;   // q pre-scale 32^-0.5
            Y[(size_t)row * 384 + col] = f2b(v);
        }
    }
}

// ---------- fused proj + LN2 + FC1/GELU + FC2 + residuals, block = 32 rows, 256 thr ----------
// LDS: x2f[32][132] f32 ~17KB + zn 8KB + hb 16KB = 41KB -> up to 3 blocks/CU.
__global__ __launch_bounds__(256) void proj_mlp(const ushort* __restrict__ aob,
                                                const ushort* __restrict__ Wp,
                                                const float* __restrict__ bp,
                                                const float* __restrict__ X,
                                                const ushort* __restrict__ W1,
                                                const float* __restrict__ b1,
                                                const ushort* __restrict__ W2,
                                                const float* __restrict__ b2,
                                                const float* __restrict__ lnw,
                                                const float* __restrict__ lnb,
                                                float* __restrict__ out) {
    __shared__ float  x2f[32 * 132];
    __shared__ ushort zn[32 * 128];
    __shared__ ushort hb[32 * 256];
    int m0 = blockIdx.x * 32;
    int wv = threadIdx.x >> 6, lane = threadIdx.x & 63;
    int lr = lane & 15, kg = lane >> 4;

    // ---- proj: wave w owns cols [w*32, +32) over 32 rows ----
    {
        int n0 = wv * 32;
        f32x4 accp[2][2] = {};
        #pragma unroll
        for (int k0 = 0; k0 < 128; k0 += 32) {
            short8 bf[2];
            #pragma unroll
            for (int ni = 0; ni < 2; ni++)
                bf[ni] = *(const short8*)(Wp + (size_t)(n0 + ni * 16 + lr) * 128 + k0 + kg * 8);
            #pragma unroll
            for (int mg = 0; mg < 2; mg++) {
                short8 a0 = *(const short8*)(aob + (size_t)(m0 + mg * 16 + lr) * 128 + k0 + kg * 8);
                #pragma unroll
                for (int ni = 0; ni < 2; ni++)
                    accp[mg][ni] = __builtin_amdgcn_mfma_f32_16x16x32_bf16(a0, bf[ni], accp[mg][ni], 0, 0, 0);
            }
        }
        #pragma unroll
        for (int mg = 0; mg < 2; mg++)
        #pragma unroll
        for (int ni = 0; ni < 2; ni++) {
            int col = n0 + ni * 16 + lr;
            float bn = bp[col];
            #pragma unroll
            for (int r = 0; r < 4; r++) {
                int row = mg * 16 + kg * 4 + r;
                x2f[row * 132 + col] = accp[mg][ni][r] + bn
                                     + X[(size_t)(m0 + row) * CDIM + col];
            }
        }
    }
    __syncthreads();

    // ---- LN2 from x2f -> zn (swizzled bf16), 4 waves x 8 rows ----
    #pragma unroll
    for (int r = 0; r < 8; r++) {
        int rl = wv * 8 + r;
        float2 v = *(const float2*)&x2f[rl * 132 + lane * 2];
        float s = v.x + v.y;
        #pragma unroll
        for (int o = 32; o > 0; o >>= 1) s += __shfl_xor(s, o);
        float mu = s * (1.0f / 128.0f);
        float d0 = v.x - mu, d1 = v.y - mu;
        float sq = d0 * d0 + d1 * d1;
        #pragma unroll
        for (int o = 32; o > 0; o >>= 1) sq += __shfl_xor(sq, o);
        float rstd = rsqrtf(sq * (1.0f / 128.0f) + 1e-5f);
        float2 wv2 = *(const float2*)(lnw + lane * 2);
        float2 bv2 = *(const float2*)(lnb + lane * 2);
        uint pk = (uint)f2b(d0 * rstd * wv2.x + bv2.x)
                | ((uint)f2b(d1 * rstd * wv2.y + bv2.y) << 16);
        *(uint*)((char*)zn + rl * 256 + ((lane * 4) ^ ((rl & 7) << 4))) = pk;
    }

    int rw0 = (wv >> 1) * 16, cw0 = (wv & 1) * 64;   // fc2 wave tile 16x64
    f32x4 acc2[4] = {};
    __syncthreads();

    #pragma unroll
    for (int p = 0; p < 2; p++) {
        // ---- fc1 + GELU: wave owns cols [p*256 + wv*64, +64) over 32 rows ----
        f32x4 acc1[2][4] = {};
        int nc0 = wv * 64;
        #pragma unroll
        for (int k0 = 0; k0 < 128; k0 += 32) {
            short8 bf[4];
            #pragma unroll
            for (int ni = 0; ni < 4; ni++)
                bf[ni] = *(const short8*)(W1 + (size_t)(p * 256 + nc0 + ni * 16 + lr) * 128 + k0 + kg * 8);
            #pragma unroll
            for (int mg = 0; mg < 2; mg++) {
                int row = mg * 16 + lr;
                short8 a0 = *(const short8*)((char*)zn + row * 256 + ((k0 * 2 + kg * 16) ^ ((row & 7) << 4)));
                #pragma unroll
                for (int ni = 0; ni < 4; ni++)
                    acc1[mg][ni] = __builtin_amdgcn_mfma_f32_16x16x32_bf16(a0, bf[ni], acc1[mg][ni], 0, 0, 0);
            }
        }
        #pragma unroll
        for (int mg = 0; mg < 2; mg++)
        #pragma unroll
        for (int ni = 0; ni < 4; ni++) {
            int lc = nc0 + ni * 16 + lr;
            float bn = b1[p * 256 + lc];
            #pragma unroll
            for (int r = 0; r < 4; r++) {
                int row = mg * 16 + kg * 4 + r;
                float v = acc1[mg][ni][r] + bn;
                // sigmoid-form tanh GELU (max dev ~3e-4 vs exact erf)
                float t = v + 0.044715f * v * v * v;
                float sg = 1.0f / (1.0f + __expf(-1.5957691216f * t));
                v = v * sg;
                *(ushort*)((char*)hb + row * 512 + ((lc * 2) ^ ((row & 7) << 4))) = f2b(v);
            }
        }
        __syncthreads();

        // ---- fc2 partial: K slice [p*256, +256) from hb ----
        #pragma unroll
        for (int k0 = 0; k0 < 256; k0 += 32) {
            int row = rw0 + lr;
            short8 a0 = *(const short8*)((char*)hb + row * 512 + ((k0 * 2 + kg * 16) ^ ((row & 7) << 4)));
            #pragma unroll
            for (int ni = 0; ni < 4; ni++) {
                short8 bf = *(const short8*)(W2 + (size_t)(cw0 + ni * 16 + lr) * 512 + p * 256 + k0 + kg * 8);
                acc2[ni] = __builtin_amdgcn_mfma_f32_16x16x32_bf16(a0, bf, acc2[ni], 0, 0, 0);
            }
        }
        __syncthreads();   // protect hb before next pass overwrites
    }

    #pragma unroll
    for (int ni = 0; ni < 4; ni++) {
        int col = cw0 + ni * 16 + lr;
        float bn = b2[col];
        #pragma unroll
        for (int r = 0; r < 4; r++) {
            int row = rw0 + kg * 4 + r;
            out[(size_t)(m0 + row) * CDIM + col] = acc2[ni][r] + bn + x2f[row * 132 + col];
        }
    }
}

// ---------- Neighborhood attention v6 (R10-validated): 2x8 pixel strip per wave ----------
__global__ __launch_bounds__(256) void nat_attn6(const ushort* __restrict__ qkv,
                                                 const float* __restrict__ rpb,
                                                 ushort* __restrict__ ao) {
    __shared__ ushort katt[8704];      // union: ks[208*32]=6656 / att 4w x 16 x 136 = 8704
    __shared__ ushort vs[32 * 232];
    __shared__ float rpl[169];
    ushort* ks = katt;

    int tid = threadIdx.x, wv = tid >> 6, lane = tid & 63;
    int lr = lane & 15, kg = lane >> 4;
    int bid = blockIdx.x;
    int blk = (bid & 7) * 98 + (bid >> 3);   // bijective XCD chunking (784 = 8*98)
    int tile = blk % 49, hb2 = blk / 49;
    int head = hb2 & 3, b = hb2 >> 2;
    int r0 = (tile / 7) * 8, c0 = (tile % 7) * 8;
    int hr0 = min(max(r0 - 3, 0), HSZ - 14);
    int hc0 = min(max(c0 - 3, 0), WSZ - 14);
    int bimg = b * HSZ * WSZ;

    if (tid < 169) rpl[tid] = rpb[head * 169 + tid];
    for (int idx = tid; idx < 784; idx += 256) {
        int t = idx >> 2, c = idx & 3;
        int gtok = bimg + (hr0 + t / 14) * WSZ + hc0 + t % 14;
        short8 v = *(const short8*)(qkv + (size_t)gtok * 384 + 128 + head * HD + c * 8);
        *(short8*)(ks + t * 32 + ((c ^ (t & 3)) << 3)) = v;
    }
    for (int idx = tid; idx < 392; idx += 256) {
        int pr = idx >> 2, c = idx & 3;
        int t = pr * 2;
        int gtok = bimg + (hr0 + t / 14) * WSZ + hc0 + t % 14;
        const ushort* vp = qkv + (size_t)gtok * 384 + 256 + head * HD + c * 8;
        short8 v0 = *(const short8*)vp;
        short8 v1 = *(const short8*)(vp + 384);
        #pragma unroll
        for (int q = 0; q < 8; q++)
            *(uint*)(vs + (c * 8 + q) * 232 + t) =
                (uint)(ushort)v0[q] | ((uint)(ushort)v1[q] << 16);
    }
    for (int idx = tid; idx < 32 * 18; idx += 256)
        *(uint*)(vs + (idx / 18) * 232 + 196 + (idx % 18) * 2) = 0;
    __syncthreads();

    int i0 = r0 + 2 * wv;
    int hw0 = min(max(i0 - 3, 0), HSZ - KS);
    int dwr = hw0 - hr0;
    int tbase = dwr * 14;
    int rb = tbase & ~7;
    int rboff = tbase - rb;

    int lpix = lr;
    int agp = bimg + (r0 + 2 * wv + (lpix >> 3)) * WSZ + c0 + (lpix & 7);
    short8 aq = *(const short8*)(qkv + (size_t)agp * 384 + head * HD + kg * 8);
    f32x4 sc[7];
    #pragma unroll
    for (int tl = 0; tl < 7; tl++) {
        int t = tbase + tl * 16 + lr;
        short8 bk = *(const short8*)(ks + t * 32 + ((kg ^ (t & 3)) << 3));
        f32x4 z = {0.f, 0.f, 0.f, 0.f};
        sc[tl] = __builtin_amdgcn_mfma_f32_16x16x32_bf16(aq, bk, z, 0, 0, 0);
    }
    __syncthreads();   // all ks reads done before att overwrites the union

    ushort* attw = katt + wv * 16 * 136;
    #pragma unroll
    for (int z = 0; z < 16; z++) {
        int ii = z * 64 + lane;
        *(uint*)(attw + (ii >> 6) * 136 + (ii & 63) * 2) = 0;
    }
    float inv[4];
    #pragma unroll
    for (int r = 0; r < 4; r++) {
        int idx = kg * 4 + r;
        int i = r0 + 2 * wv + (idx >> 3), j = c0 + (idx & 7);
        int shh = min(max(i - 3, 0), HSZ - KS);
        int sww = min(max(j - 3, 0), WSZ - KS);
        int dih = shh - hr0, dj = sww - hc0;
        int offh = hr0 - i + 6, offw = hc0 - j + 6;
        float sv[7];
        float mx = -1e30f;
        #pragma unroll
        for (int tl = 0; tl < 7; tl++) {
            int t = tbase + tl * 16 + lr;
            int thr = (unsigned)t / 14u;
            int twr = t - thr * 14;
            bool in = ((unsigned)(thr - dih) < 7u) && ((unsigned)(twr - dj) < 7u);
            int bidx = (thr + offh) * 13 + (twr + offw);
            bidx = min(max(bidx, 0), 168);
            float s = sc[tl][r] + rpl[bidx];
            sv[tl] = in ? s : -1e30f;
            mx = fmaxf(mx, sv[tl]);
        }
        #pragma unroll
        for (int o = 8; o > 0; o >>= 1) mx = fmaxf(mx, __shfl_xor(mx, o));
        float sum = 0.f;
        #pragma unroll
        for (int tl = 0; tl < 7; tl++) {
            float e = __expf(sv[tl] - mx);
            sum += e;
            attw[idx * 136 + rboff + tl * 16 + lr] = f2b(e);
        }
        #pragma unroll
        for (int o = 8; o > 0; o >>= 1) sum += __shfl_xor(sum, o);
        inv[r] = 1.0f / sum;
    }

    f32x4 po[2] = {};
    #pragma unroll
    for (int kst = 0; kst < 4; kst++) {
        short8 pa = *(const short8*)(attw + lr * 136 + kst * 32 + kg * 8);
        #pragma unroll
        for (int n = 0; n < 2; n++) {
            short8 vb = *(const short8*)(vs + (n * 16 + lr) * 232 + rb + kst * 32 + kg * 8);
            po[n] = __builtin_amdgcn_mfma_f32_16x16x32_bf16(pa, vb, po[n], 0, 0, 0);
        }
    }

    #pragma unroll
    for (int n = 0; n < 2; n++)
    #pragma unroll
    for (int rr = 0; rr < 4; rr++) {
        int idx = kg * 4 + rr;
        int gp = bimg + (r0 + 2 * wv + (idx >> 3)) * WSZ + c0 + (idx & 7);
        ao[(size_t)gp * CDIM + head * HD + n * 16 + lr] = f2b(po[n][rr] * inv[rr]);
    }
}

extern "C" void kernel_launch(void* const* d_in, const int* in_sizes, int n_in,
                              void* d_out, int out_size, void* d_ws, size_t ws_size,
                              hipStream_t stream) {
    const float* x      = (const float*)d_in[0];
    const float* n1w    = (const float*)d_in[1];
    const float* n1b    = (const float*)d_in[2];
    const float* qkv_w  = (const float*)d_in[3];
    const float* qkv_b  = (const float*)d_in[4];
    const float* rpb    = (const float*)d_in[5];
    const float* proj_w = (const float*)d_in[6];
    const float* proj_b = (const float*)d_in[7];
    const float* n2w    = (const float*)d_in[8];
    const float* n2b    = (const float*)d_in[9];
    const float* fc1_w  = (const float*)d_in[10];
    const float* fc1_b  = (const float*)d_in[11];
    const float* fc2_w  = (const float*)d_in[12];
    const float* fc2_b  = (const float*)d_in[13];
    float* out = (float*)d_out;

    ushort* wb   = (ushort*)d_ws;                        // 196608 bf16 weights
    ushort* qkvb = wb + 196608;                          // TOK*384 bf16 (q scaled)
    ushort* aob  = qkvb + (size_t)TOK * 384;             // TOK*128 bf16

    const ushort* w_qkv  = wb;
    const ushort* w_proj = wb + 49152;
    const ushort* w_fc1  = wb + 65536;
    const ushort* w_fc2  = wb + 131072;

    convert_w<<<192, 256, 0, stream>>>(qkv_w, proj_w, fc1_w, fc2_w, wb);
    ln1_qkv<<<TOK / 32, 256, 0, stream>>>(x, w_qkv, qkv_b, n1w, n1b, qkvb);
    nat_attn6<<<4 * NHEAD * 49, 256, 0, stream>>>(qkvb, rpb, aob);
    proj_mlp<<<TOK / 32, 256, 0, stream>>>(aob, w_proj, proj_b, x,
                                           w_fc1, fc1_b, w_fc2, fc2_b, n2w, n2b, out);
}

// Round 12
// 59.290 us; speedup vs baseline: 1.1592x; 1.1592x over previous
//
#include <hip/hip_runtime.h>
#include <math.h>

#define TOK 12544   // B*H*W
#define CDIM 128
#define NHEAD 4
#define HD 32
#define KS 7
#define HSZ 56
#define WSZ 56

typedef __attribute__((ext_vector_type(8))) short short8;   // bf16x8 mfma frag
typedef __attribute__((ext_vector_type(4))) float f32x4;

__device__ inline ushort f2b(float f) {                      // fp32 -> bf16 RNE
    uint u = __float_as_uint(f);
    u += 0x7fffu + ((u >> 16) & 1u);
    return (ushort)(u >> 16);
}

// ---------- convert the 4 weight matrices to bf16 into one contiguous buffer ----------
__global__ void convert_w(const float* __restrict__ a, const float* __restrict__ b,
                          const float* __restrict__ c, const float* __restrict__ d,
                          ushort* __restrict__ wb) {
    int e = (blockIdx.x * 256 + threadIdx.x) * 4;
    const float* src;
    if (e < 49152)       src = a + e;
    else if (e < 65536)  src = b + (e - 49152);
    else if (e < 131072) src = c + (e - 65536);
    else                 src = d + (e - 131072);
    float4 v = *(const float4*)src;
    uint2 pk;
    pk.x = (uint)f2b(v.x) | ((uint)f2b(v.y) << 16);
    pk.y = (uint)f2b(v.z) | ((uint)f2b(v.w) << 16);
    *(uint2*)(wb + e) = pk;
}

// ---------- helper: LN of a 64-row tile into swizzled LDS (bf16), 8 waves ----------
__device__ inline void ln_to_lds(const float* __restrict__ X, int m0,
                                 const float* __restrict__ lnw, const float* __restrict__ lnb,
                                 ushort* __restrict__ lds) {
    int wv = threadIdx.x >> 6, lane = threadIdx.x & 63;
    #pragma unroll
    for (int r = 0; r < 8; r++) {
        int rl = wv * 8 + r;
        float2 v = *(const float2*)(X + (size_t)(m0 + rl) * CDIM + lane * 2);
        float s = v.x + v.y;
        #pragma unroll
        for (int o = 32; o > 0; o >>= 1) s += __shfl_xor(s, o);
        float mu = s * (1.0f / 128.0f);
        float d0 = v.x - mu, d1 = v.y - mu;
        float sq = d0 * d0 + d1 * d1;
        #pragma unroll
        for (int o = 32; o > 0; o >>= 1) sq += __shfl_xor(sq, o);
        float rstd = rsqrtf(sq * (1.0f / 128.0f) + 1e-5f);
        float2 wv2 = *(const float2*)(lnw + lane * 2);
        float2 bv2 = *(const float2*)(lnb + lane * 2);
        uint pk = (uint)f2b(d0 * rstd * wv2.x + bv2.x)
                | ((uint)f2b(d1 * rstd * wv2.y + bv2.y) << 16);
        *(uint*)((char*)lds + rl * 256 + ((lane * 4) ^ ((rl & 7) << 4))) = pk;
    }
}

// ---------- fused LN1 + QKV GEMM: block = 64 rows x 384 cols, 512 thr (R10) ----------
// Output layout head-major: qkv[(which*4+head)*TOK + tok][32] bf16 (q pre-scaled).
__global__ __launch_bounds__(512) void ln1_qkv(const float* __restrict__ X,
                                               const ushort* __restrict__ W,
                                               const float* __restrict__ bias,
                                               const float* __restrict__ lnw,
                                               const float* __restrict__ lnb,
                                               ushort* __restrict__ Y) {
    __shared__ ushort xn[64 * 128];   // 16 KB swizzled
    int m0 = blockIdx.x * 64;
    ln_to_lds(X, m0, lnw, lnb, xn);
    __syncthreads();

    int wv = threadIdx.x >> 6, lane = threadIdx.x & 63;
    int lr = lane & 15, kg = lane >> 4;
    int n0 = wv * 48;
    f32x4 acc[4][3] = {};
    #pragma unroll
    for (int k0 = 0; k0 < 128; k0 += 32) {
        short8 bf[3];
        #pragma unroll
        for (int ni = 0; ni < 3; ni++)
            bf[ni] = *(const short8*)(W + (size_t)(n0 + ni * 16 + lr) * 128 + k0 + kg * 8);
        #pragma unroll
        for (int mg = 0; mg < 4; mg++) {
            int row = mg * 16 + lr;
            short8 a0 = *(const short8*)((char*)xn + row * 256 + ((k0 * 2 + kg * 16) ^ ((row & 7) << 4)));
            #pragma unroll
            for (int ni = 0; ni < 3; ni++)
                acc[mg][ni] = __builtin_amdgcn_mfma_f32_16x16x32_bf16(a0, bf[ni], acc[mg][ni], 0, 0, 0);
        }
    }
    #pragma unroll
    for (int mg = 0; mg < 4; mg++)
    #pragma unroll
    for (int ni = 0; ni < 3; ni++) {
        int base = n0 + ni * 16;            // multiple of 16
        int which = base >> 7;              // 0=q 1=k 2=v
        int rem   = base & 127;
        int head  = rem >> 5;
        int hd0   = rem & 31;               // 0 or 16
        float bn = bias[base + lr];
        float sc = (which == 0) ? 0.17677669529663687f : 1.0f;
        ushort* dst = Y + ((size_t)(which * 4 + head) * TOK) * HD + hd0 + lr;
        #pragma unroll
        for (int r = 0; r < 4; r++) {
            int row = m0 + mg * 16 + kg * 4 + r;
            float v = (acc[mg][ni][r] + bn) * sc;
            dst[(size_t)row * HD] = f2b(v);
        }
    }
}

// ---------- fused proj + LN2 + FC1/GELU + FC2 + residuals, block = 64 rows (R10) ----------
__global__ __launch_bounds__(512) void proj_mlp(const ushort* __restrict__ aob,
                                                const ushort* __restrict__ Wp,
                                                const float* __restrict__ bp,
                                                const float* __restrict__ X,
                                                const ushort* __restrict__ W1,
                                                const float* __restrict__ b1,
                                                const ushort* __restrict__ W2,
                                                const float* __restrict__ b2,
                                                const float* __restrict__ lnw,
                                                const float* __restrict__ lnb,
                                                float* __restrict__ out) {
    __shared__ float  x2f[64 * 132];  // stride 132 breaks epilogue bank aliasing
    __shared__ ushort zn[64 * 128];   // 16 KB swizzled
    __shared__ ushort hb[64 * 256];   // 32 KB swizzled
    int m0 = blockIdx.x * 64;
    int wv = threadIdx.x >> 6, lane = threadIdx.x & 63;
    int lr = lane & 15, kg = lane >> 4;

    // ---- proj: wave w owns cols [w*16, +16) over all 64 rows ----
    {
        int n0 = wv * 16;
        f32x4 accp[4] = {};
        #pragma unroll
        for (int k0 = 0; k0 < 128; k0 += 32) {
            short8 bf = *(const short8*)(Wp + (size_t)(n0 + lr) * 128 + k0 + kg * 8);
            #pragma unroll
            for (int mg = 0; mg < 4; mg++) {
                short8 a0 = *(const short8*)(aob + (size_t)(m0 + mg * 16 + lr) * 128 + k0 + kg * 8);
                accp[mg] = __builtin_amdgcn_mfma_f32_16x16x32_bf16(a0, bf, accp[mg], 0, 0, 0);
            }
        }
        float bn = bp[n0 + lr];
        #pragma unroll
        for (int mg = 0; mg < 4; mg++)
        #pragma unroll
        for (int r = 0; r < 4; r++) {
            int row = mg * 16 + kg * 4 + r;
            x2f[row * 132 + n0 + lr] = accp[mg][r] + bn
                                     + X[(size_t)(m0 + row) * CDIM + n0 + lr];
        }
    }
    __syncthreads();

    // ---- LN2 from x2f -> zn (swizzled bf16) ----
    #pragma unroll
    for (int r = 0; r < 8; r++) {
        int rl = wv * 8 + r;
        float2 v = *(const float2*)&x2f[rl * 132 + lane * 2];
        float s = v.x + v.y;
        #pragma unroll
        for (int o = 32; o > 0; o >>= 1) s += __shfl_xor(s, o);
        float mu = s * (1.0f / 128.0f);
        float d0 = v.x - mu, d1 = v.y - mu;
        float sq = d0 * d0 + d1 * d1;
        #pragma unroll
        for (int o = 32; o > 0; o >>= 1) sq += __shfl_xor(sq, o);
        float rstd = rsqrtf(sq * (1.0f / 128.0f) + 1e-5f);
        float2 wv2 = *(const float2*)(lnw + lane * 2);
        float2 bv2 = *(const float2*)(lnb + lane * 2);
        uint pk = (uint)f2b(d0 * rstd * wv2.x + bv2.x)
                | ((uint)f2b(d1 * rstd * wv2.y + bv2.y) << 16);
        *(uint*)((char*)zn + rl * 256 + ((lane * 4) ^ ((rl & 7) << 4))) = pk;
    }

    int rw0 = (wv >> 2) * 32, cw0 = (wv & 3) * 32;   // fc2 wave tile 32x32
    f32x4 acc2[2][2] = {};
    __syncthreads();

    #pragma unroll
    for (int p = 0; p < 2; p++) {
        // ---- fc1 + GELU: wave owns cols [p*256 + wv*32, +32) over all 64 rows ----
        f32x4 acc1[4][2] = {};
        int nc0 = wv * 32;
        #pragma unroll
        for (int k0 = 0; k0 < 128; k0 += 32) {
            short8 bf[2];
            #pragma unroll
            for (int ni = 0; ni < 2; ni++)
                bf[ni] = *(const short8*)(W1 + (size_t)(p * 256 + nc0 + ni * 16 + lr) * 128 + k0 + kg * 8);
            #pragma unroll
            for (int mg = 0; mg < 4; mg++) {
                int row = mg * 16 + lr;
                short8 a0 = *(const short8*)((char*)zn + row * 256 + ((k0 * 2 + kg * 16) ^ ((row & 7) << 4)));
                #pragma unroll
                for (int ni = 0; ni < 2; ni++)
                    acc1[mg][ni] = __builtin_amdgcn_mfma_f32_16x16x32_bf16(a0, bf[ni], acc1[mg][ni], 0, 0, 0);
            }
        }
        #pragma unroll
        for (int mg = 0; mg < 4; mg++)
        #pragma unroll
        for (int ni = 0; ni < 2; ni++) {
            int lc = nc0 + ni * 16 + lr;
            float bn = b1[p * 256 + lc];
            #pragma unroll
            for (int r = 0; r < 4; r++) {
                int row = mg * 16 + kg * 4 + r;
                float v = acc1[mg][ni][r] + bn;
                // sigmoid-form tanh GELU (max dev ~3e-4 vs exact erf)
                float t = v + 0.044715f * v * v * v;
                float sg = 1.0f / (1.0f + __expf(-1.5957691216f * t));
                v = v * sg;
                *(ushort*)((char*)hb + row * 512 + ((lc * 2) ^ ((row & 7) << 4))) = f2b(v);
            }
        }
        __syncthreads();

        // ---- fc2 partial: K slice [p*256, +256) from hb ----
        #pragma unroll
        for (int k0 = 0; k0 < 256; k0 += 32) {
            short8 a0[2], bf[2];
            #pragma unroll
            for (int mi = 0; mi < 2; mi++) {
                int row = rw0 + mi * 16 + lr;
                a0[mi] = *(const short8*)((char*)hb + row * 512 + ((k0 * 2 + kg * 16) ^ ((row & 7) << 4)));
            }
            #pragma unroll
            for (int ni = 0; ni < 2; ni++)
                bf[ni] = *(const short8*)(W2 + (size_t)(cw0 + ni * 16 + lr) * 512 + p * 256 + k0 + kg * 8);
            #pragma unroll
            for (int mi = 0; mi < 2; mi++)
            #pragma unroll
            for (int ni = 0; ni < 2; ni++)
                acc2[mi][ni] = __builtin_amdgcn_mfma_f32_16x16x32_bf16(a0[mi], bf[ni], acc2[mi][ni], 0, 0, 0);
        }
        __syncthreads();   // protect hb before next pass overwrites
    }

    #pragma unroll
    for (int mi = 0; mi < 2; mi++)
    #pragma unroll
    for (int ni = 0; ni < 2; ni++) {
        int col = cw0 + ni * 16 + lr;
        float bn = b2[col];
        #pragma unroll
        for (int r = 0; r < 4; r++) {
            int row = rw0 + mi * 16 + kg * 4 + r;
            out[(size_t)(m0 + row) * CDIM + col] = acc2[mi][ni][r] + bn + x2f[row * 132 + col];
        }
    }
}

// ---------- Neighborhood attention v7: R10 structure + head-major qkv reads ----------
__global__ __launch_bounds__(256) void nat_attn7(const ushort* __restrict__ qkv,
                                                 const float* __restrict__ rpb,
                                                 ushort* __restrict__ ao) {
    __shared__ ushort katt[8704];      // union: ks[208*32]=6656 / att 4w x 16 x 136 = 8704
    __shared__ ushort vs[32 * 232];
    __shared__ float rpl[169];
    ushort* ks = katt;

    int tid = threadIdx.x, wv = tid >> 6, lane = tid & 63;
    int lr = lane & 15, kg = lane >> 4;
    int bid = blockIdx.x;
    int blk = (bid & 7) * 98 + (bid >> 3);   // bijective XCD chunking (784 = 8*98)
    int tile = blk % 49, hb2 = blk / 49;
    int head = hb2 & 3, b = hb2 >> 2;
    int r0 = (tile / 7) * 8, c0 = (tile % 7) * 8;
    int hr0 = min(max(r0 - 3, 0), HSZ - 14);
    int hc0 = min(max(c0 - 3, 0), WSZ - 14);
    int bimg = b * HSZ * WSZ;

    const ushort* qb = qkv + (size_t)(0 + head) * TOK * HD;
    const ushort* kb = qkv + (size_t)(4 + head) * TOK * HD;
    const ushort* vb = qkv + (size_t)(8 + head) * TOK * HD;

    // ---- phase 0: stage K (swizzled slots), V transposed (paired), rpb ----
    if (tid < 169) rpl[tid] = rpb[head * 169 + tid];
    for (int idx = tid; idx < 784; idx += 256) {
        int t = idx >> 2, c = idx & 3;
        int gtok = bimg + (hr0 + t / 14) * WSZ + hc0 + t % 14;
        short8 v = *(const short8*)(kb + (size_t)gtok * HD + c * 8);
        *(short8*)(ks + t * 32 + ((c ^ (t & 3)) << 3)) = v;
    }
    for (int idx = tid; idx < 392; idx += 256) {
        int pr = idx >> 2, c = idx & 3;
        int t = pr * 2;
        int gtok = bimg + (hr0 + t / 14) * WSZ + hc0 + t % 14;
        const ushort* vp = vb + (size_t)gtok * HD + c * 8;
        short8 v0 = *(const short8*)vp;
        short8 v1 = *(const short8*)(vp + HD);
        #pragma unroll
        for (int q = 0; q < 8; q++)
            *(uint*)(vs + (c * 8 + q) * 232 + t) =
                (uint)(ushort)v0[q] | ((uint)(ushort)v1[q] << 16);
    }
    for (int idx = tid; idx < 32 * 18; idx += 256)
        *(uint*)(vs + (idx / 18) * 232 + 196 + (idx % 18) * 2) = 0;
    __syncthreads();

    int i0 = r0 + 2 * wv;
    int hw0 = min(max(i0 - 3, 0), HSZ - KS);
    int dwr = hw0 - hr0;
    int tbase = dwr * 14;
    int rb = tbase & ~7;
    int rboff = tbase - rb;

    int lpix = lr;
    int agp = bimg + (r0 + 2 * wv + (lpix >> 3)) * WSZ + c0 + (lpix & 7);
    short8 aq = *(const short8*)(qb + (size_t)agp * HD + kg * 8);
    f32x4 sc[7];
    #pragma unroll
    for (int tl = 0; tl < 7; tl++) {
        int t = tbase + tl * 16 + lr;
        short8 bk = *(const short8*)(ks + t * 32 + ((kg ^ (t & 3)) << 3));
        f32x4 z = {0.f, 0.f, 0.f, 0.f};
        sc[tl] = __builtin_amdgcn_mfma_f32_16x16x32_bf16(aq, bk, z, 0, 0, 0);
    }
    __syncthreads();   // all ks reads done before att overwrites the union

    ushort* attw = katt + wv * 16 * 136;
    #pragma unroll
    for (int z = 0; z < 16; z++) {
        int ii = z * 64 + lane;
        *(uint*)(attw + (ii >> 6) * 136 + (ii & 63) * 2) = 0;
    }
    float inv[4];
    #pragma unroll
    for (int r = 0; r < 4; r++) {
        int idx = kg * 4 + r;
        int i = r0 + 2 * wv + (idx >> 3), j = c0 + (idx & 7);
        int shh = min(max(i - 3, 0), HSZ - KS);
        int sww = min(max(j - 3, 0), WSZ - KS);
        int dih = shh - hr0, dj = sww - hc0;
        int offh = hr0 - i + 6, offw = hc0 - j + 6;
        float sv[7];
        float mx = -1e30f;
        #pragma unroll
        for (int tl = 0; tl < 7; tl++) {
            int t = tbase + tl * 16 + lr;
            int thr = (unsigned)t / 14u;
            int twr = t - thr * 14;
            bool in = ((unsigned)(thr - dih) < 7u) && ((unsigned)(twr - dj) < 7u);
            int bidx = (thr + offh) * 13 + (twr + offw);
            bidx = min(max(bidx, 0), 168);
            float s = sc[tl][r] + rpl[bidx];
            sv[tl] = in ? s : -1e30f;
            mx = fmaxf(mx, sv[tl]);
        }
        #pragma unroll
        for (int o = 8; o > 0; o >>= 1) mx = fmaxf(mx, __shfl_xor(mx, o));
        float sum = 0.f;
        #pragma unroll
        for (int tl = 0; tl < 7; tl++) {
            float e = __expf(sv[tl] - mx);
            sum += e;
            attw[idx * 136 + rboff + tl * 16 + lr] = f2b(e);
        }
        #pragma unroll
        for (int o = 8; o > 0; o >>= 1) sum += __shfl_xor(sum, o);
        inv[r] = 1.0f / sum;
    }

    f32x4 po[2] = {};
    #pragma unroll
    for (int kst = 0; kst < 4; kst++) {
        short8 pa = *(const short8*)(attw + lr * 136 + kst * 32 + kg * 8);
        #pragma unroll
        for (int n = 0; n < 2; n++) {
            short8 vbf = *(const short8*)(vs + (n * 16 + lr) * 232 + rb + kst * 32 + kg * 8);
            po[n] = __builtin_amdgcn_mfma_f32_16x16x32_bf16(pa, vbf, po[n], 0, 0, 0);
        }
    }

    #pragma unroll
    for (int n = 0; n < 2; n++)
    #pragma unroll
    for (int rr = 0; rr < 4; rr++) {
        int idx = kg * 4 + rr;
        int gp = bimg + (r0 + 2 * wv + (idx >> 3)) * WSZ + c0 + (idx & 7);
        ao[(size_t)gp * CDIM + head * HD + n * 16 + lr] = f2b(po[n][rr] * inv[rr]);
    }
}

extern "C" void kernel_launch(void* const* d_in, const int* in_sizes, int n_in,
                              void* d_out, int out_size, void* d_ws, size_t ws_size,
                              hipStream_t stream) {
    const float* x      = (const float*)d_in[0];
    const float* n1w    = (const float*)d_in[1];
    const float* n1b    = (const float*)d_in[2];
    const float* qkv_w  = (const float*)d_in[3];
    const float* qkv_b  = (const float*)d_in[4];
    const float* rpb    = (const float*)d_in[5];
    const float* proj_w = (const float*)d_in[6];
    const float* proj_b = (const float*)d_in[7];
    const float* n2w    = (const float*)d_in[8];
    const float* n2b    = (const float*)d_in[9];
    const float* fc1_w  = (const float*)d_in[10];
    const float* fc1_b  = (const float*)d_in[11];
    const float* fc2_w  = (const float*)d_in[12];
    const float* fc2_b  = (const float*)d_in[13];
    float* out = (float*)d_out;

    ushort* wb   = (ushort*)d_ws;                        // 196608 bf16 weights
    ushort* qkvb = wb + 196608;                          // [3][4][TOK][32] bf16
    ushort* aob  = qkvb + (size_t)TOK * 384;             // TOK*128 bf16

    const ushort* w_qkv  = wb;
    const ushort* w_proj = wb + 49152;
    const ushort* w_fc1  = wb + 65536;
    const ushort* w_fc2  = wb + 131072;

    convert_w<<<192, 256, 0, stream>>>(qkv_w, proj_w, fc1_w, fc2_w, wb);
    ln1_qkv<<<TOK / 64, 512, 0, stream>>>(x, w_qkv, qkv_b, n1w, n1b, qkvb);
    nat_attn7<<<4 * NHEAD * 49, 256, 0, stream>>>(qkvb, rpb, aob);
    proj_mlp<<<TOK / 64, 512, 0, stream>>>(aob, w_proj, proj_b, x,
                                           w_fc1, fc1_b, w_fc2, fc2_b, n2w, n2b, out);
}

// Round 13
// 58.544 us; speedup vs baseline: 1.1740x; 1.0128x over previous
//
#include <hip/hip_runtime.h>
#include <math.h>

#define TOK 12544   // B*H*W
#define CDIM 128
#define NHEAD 4
#define HD 32
#define KS 7
#define HSZ 56
#define WSZ 56

typedef __attribute__((ext_vector_type(8))) short short8;   // bf16x8 mfma frag
typedef __attribute__((ext_vector_type(4))) float f32x4;

__device__ inline ushort f2b(float f) {                      // fp32 -> bf16 RNE
    uint u = __float_as_uint(f);
    u += 0x7fffu + ((u >> 16) & 1u);
    return (ushort)(u >> 16);
}

// ---------- convert the 4 weight matrices to bf16 into one contiguous buffer ----------
__global__ void convert_w(const float* __restrict__ a, const float* __restrict__ b,
                          const float* __restrict__ c, const float* __restrict__ d,
                          ushort* __restrict__ wb) {
    int e = (blockIdx.x * 256 + threadIdx.x) * 4;
    const float* src;
    if (e < 49152)       src = a + e;
    else if (e < 65536)  src = b + (e - 49152);
    else if (e < 131072) src = c + (e - 65536);
    else                 src = d + (e - 131072);
    float4 v = *(const float4*)src;
    uint2 pk;
    pk.x = (uint)f2b(v.x) | ((uint)f2b(v.y) << 16);
    pk.y = (uint)f2b(v.z) | ((uint)f2b(v.w) << 16);
    *(uint2*)(wb + e) = pk;
}

// ---------- helper: LN of a 64-row tile into swizzled LDS (bf16), 8 waves ----------
__device__ inline void ln_to_lds(const float* __restrict__ X, int m0,
                                 const float* __restrict__ lnw, const float* __restrict__ lnb,
                                 ushort* __restrict__ lds) {
    int wv = threadIdx.x >> 6, lane = threadIdx.x & 63;
    #pragma unroll
    for (int r = 0; r < 8; r++) {
        int rl = wv * 8 + r;
        float2 v = *(const float2*)(X + (size_t)(m0 + rl) * CDIM + lane * 2);
        float s = v.x + v.y;
        #pragma unroll
        for (int o = 32; o > 0; o >>= 1) s += __shfl_xor(s, o);
        float mu = s * (1.0f / 128.0f);
        float d0 = v.x - mu, d1 = v.y - mu;
        float sq = d0 * d0 + d1 * d1;
        #pragma unroll
        for (int o = 32; o > 0; o >>= 1) sq += __shfl_xor(sq, o);
        float rstd = rsqrtf(sq * (1.0f / 128.0f) + 1e-5f);
        float2 wv2 = *(const float2*)(lnw + lane * 2);
        float2 bv2 = *(const float2*)(lnb + lane * 2);
        uint pk = (uint)f2b(d0 * rstd * wv2.x + bv2.x)
                | ((uint)f2b(d1 * rstd * wv2.y + bv2.y) << 16);
        *(uint*)((char*)lds + rl * 256 + ((lane * 4) ^ ((rl & 7) << 4))) = pk;
    }
}

// ---------- fused LN1 + QKV GEMM: block = 64 rows x 384 cols, 512 thr (R12) ----------
// Output layout head-major: qkv[(which*4+head)*TOK + tok][32] bf16 (q pre-scaled).
__global__ __launch_bounds__(512) void ln1_qkv(const float* __restrict__ X,
                                               const ushort* __restrict__ W,
                                               const float* __restrict__ bias,
                                               const float* __restrict__ lnw,
                                               const float* __restrict__ lnb,
                                               ushort* __restrict__ Y) {
    __shared__ ushort xn[64 * 128];   // 16 KB swizzled
    int m0 = blockIdx.x * 64;
    ln_to_lds(X, m0, lnw, lnb, xn);
    __syncthreads();

    int wv = threadIdx.x >> 6, lane = threadIdx.x & 63;
    int lr = lane & 15, kg = lane >> 4;
    int n0 = wv * 48;
    f32x4 acc[4][3] = {};
    #pragma unroll
    for (int k0 = 0; k0 < 128; k0 += 32) {
        short8 bf[3];
        #pragma unroll
        for (int ni = 0; ni < 3; ni++)
            bf[ni] = *(const short8*)(W + (size_t)(n0 + ni * 16 + lr) * 128 + k0 + kg * 8);
        #pragma unroll
        for (int mg = 0; mg < 4; mg++) {
            int row = mg * 16 + lr;
            short8 a0 = *(const short8*)((char*)xn + row * 256 + ((k0 * 2 + kg * 16) ^ ((row & 7) << 4)));
            #pragma unroll
            for (int ni = 0; ni < 3; ni++)
                acc[mg][ni] = __builtin_amdgcn_mfma_f32_16x16x32_bf16(a0, bf[ni], acc[mg][ni], 0, 0, 0);
        }
    }
    #pragma unroll
    for (int mg = 0; mg < 4; mg++)
    #pragma unroll
    for (int ni = 0; ni < 3; ni++) {
        int base = n0 + ni * 16;            // multiple of 16
        int which = base >> 7;              // 0=q 1=k 2=v
        int rem   = base & 127;
        int head  = rem >> 5;
        int hd0   = rem & 31;               // 0 or 16
        float bn = bias[base + lr];
        float sc = (which == 0) ? 0.17677669529663687f : 1.0f;
        ushort* dst = Y + ((size_t)(which * 4 + head) * TOK) * HD + hd0 + lr;
        #pragma unroll
        for (int r = 0; r < 4; r++) {
            int row = m0 + mg * 16 + kg * 4 + r;
            float v = (acc[mg][ni][r] + bn) * sc;
            dst[(size_t)row * HD] = f2b(v);
        }
    }
}

// ---------- fused proj + LN2 + FC1/GELU + FC2 + residuals, single-pass MLP ----------
// 512 thr (8 waves). LDS: x2f 33KB + zn 16KB + hb[64][512] 64KB = 113KB, 1 block/CU.
__global__ __launch_bounds__(512) void proj_mlp(const ushort* __restrict__ aob,
                                                const ushort* __restrict__ Wp,
                                                const float* __restrict__ bp,
                                                const float* __restrict__ X,
                                                const ushort* __restrict__ W1,
                                                const float* __restrict__ b1,
                                                const ushort* __restrict__ W2,
                                                const float* __restrict__ b2,
                                                const float* __restrict__ lnw,
                                                const float* __restrict__ lnb,
                                                float* __restrict__ out) {
    __shared__ float  x2f[64 * 132];  // stride 132 breaks epilogue bank aliasing
    __shared__ ushort zn[64 * 128];   // 16 KB swizzled
    __shared__ ushort hb[64 * 512];   // 64 KB swizzled
    int m0 = blockIdx.x * 64;
    int wv = threadIdx.x >> 6, lane = threadIdx.x & 63;
    int lr = lane & 15, kg = lane >> 4;

    // ---- proj: wave w owns cols [w*16, +16) over all 64 rows ----
    {
        int n0 = wv * 16;
        f32x4 accp[4] = {};
        #pragma unroll
        for (int k0 = 0; k0 < 128; k0 += 32) {
            short8 bf = *(const short8*)(Wp + (size_t)(n0 + lr) * 128 + k0 + kg * 8);
            #pragma unroll
            for (int mg = 0; mg < 4; mg++) {
                short8 a0 = *(const short8*)(aob + (size_t)(m0 + mg * 16 + lr) * 128 + k0 + kg * 8);
                accp[mg] = __builtin_amdgcn_mfma_f32_16x16x32_bf16(a0, bf, accp[mg], 0, 0, 0);
            }
        }
        float bn = bp[n0 + lr];
        #pragma unroll
        for (int mg = 0; mg < 4; mg++)
        #pragma unroll
        for (int r = 0; r < 4; r++) {
            int row = mg * 16 + kg * 4 + r;
            x2f[row * 132 + n0 + lr] = accp[mg][r] + bn
                                     + X[(size_t)(m0 + row) * CDIM + n0 + lr];
        }
    }
    __syncthreads();

    // ---- LN2 from x2f -> zn (swizzled bf16) ----
    #pragma unroll
    for (int r = 0; r < 8; r++) {
        int rl = wv * 8 + r;
        float2 v = *(const float2*)&x2f[rl * 132 + lane * 2];
        float s = v.x + v.y;
        #pragma unroll
        for (int o = 32; o > 0; o >>= 1) s += __shfl_xor(s, o);
        float mu = s * (1.0f / 128.0f);
        float d0 = v.x - mu, d1 = v.y - mu;
        float sq = d0 * d0 + d1 * d1;
        #pragma unroll
        for (int o = 32; o > 0; o >>= 1) sq += __shfl_xor(sq, o);
        float rstd = rsqrtf(sq * (1.0f / 128.0f) + 1e-5f);
        float2 wv2 = *(const float2*)(lnw + lane * 2);
        float2 bv2 = *(const float2*)(lnb + lane * 2);
        uint pk = (uint)f2b(d0 * rstd * wv2.x + bv2.x)
                | ((uint)f2b(d1 * rstd * wv2.y + bv2.y) << 16);
        *(uint*)((char*)zn + rl * 256 + ((lane * 4) ^ ((rl & 7) << 4))) = pk;
    }
    __syncthreads();

    // ---- fc1 + GELU single pass: wave owns cols [wv*64, +64) over all 64 rows ----
    {
        f32x4 acc1[4][4] = {};
        int nc0 = wv * 64;
        #pragma unroll
        for (int k0 = 0; k0 < 128; k0 += 32) {
            short8 bf[4];
            #pragma unroll
            for (int ni = 0; ni < 4; ni++)
                bf[ni] = *(const short8*)(W1 + (size_t)(nc0 + ni * 16 + lr) * 128 + k0 + kg * 8);
            #pragma unroll
            for (int mg = 0; mg < 4; mg++) {
                int row = mg * 16 + lr;
                short8 a0 = *(const short8*)((char*)zn + row * 256 + ((k0 * 2 + kg * 16) ^ ((row & 7) << 4)));
                #pragma unroll
                for (int ni = 0; ni < 4; ni++)
                    acc1[mg][ni] = __builtin_amdgcn_mfma_f32_16x16x32_bf16(a0, bf[ni], acc1[mg][ni], 0, 0, 0);
            }
        }
        #pragma unroll
        for (int mg = 0; mg < 4; mg++)
        #pragma unroll
        for (int ni = 0; ni < 4; ni++) {
            int lc = nc0 + ni * 16 + lr;
            float bn = b1[lc];
            #pragma unroll
            for (int r = 0; r < 4; r++) {
                int row = mg * 16 + kg * 4 + r;
                float v = acc1[mg][ni][r] + bn;
                // sigmoid-form tanh GELU (max dev ~3e-4 vs exact erf)
                float t = v + 0.044715f * v * v * v;
                float sg = 1.0f / (1.0f + __expf(-1.5957691216f * t));
                v = v * sg;
                *(ushort*)((char*)hb + row * 1024 + ((lc * 2) ^ ((row & 7) << 4))) = f2b(v);
            }
        }
    }
    __syncthreads();

    // ---- fc2: unbroken K = 512 loop from hb ----
    int rw0 = (wv >> 2) * 32, cw0 = (wv & 3) * 32;   // fc2 wave tile 32x32
    f32x4 acc2[2][2] = {};
    #pragma unroll
    for (int k0 = 0; k0 < 512; k0 += 32) {
        short8 a0[2], bf[2];
        #pragma unroll
        for (int mi = 0; mi < 2; mi++) {
            int row = rw0 + mi * 16 + lr;
            a0[mi] = *(const short8*)((char*)hb + row * 1024 + ((k0 * 2 + kg * 16) ^ ((row & 7) << 4)));
        }
        #pragma unroll
        for (int ni = 0; ni < 2; ni++)
            bf[ni] = *(const short8*)(W2 + (size_t)(cw0 + ni * 16 + lr) * 512 + k0 + kg * 8);
        #pragma unroll
        for (int mi = 0; mi < 2; mi++)
        #pragma unroll
        for (int ni = 0; ni < 2; ni++)
            acc2[mi][ni] = __builtin_amdgcn_mfma_f32_16x16x32_bf16(a0[mi], bf[ni], acc2[mi][ni], 0, 0, 0);
    }

    #pragma unroll
    for (int mi = 0; mi < 2; mi++)
    #pragma unroll
    for (int ni = 0; ni < 2; ni++) {
        int col = cw0 + ni * 16 + lr;
        float bn = b2[col];
        #pragma unroll
        for (int r = 0; r < 4; r++) {
            int row = rw0 + mi * 16 + kg * 4 + r;
            out[(size_t)(m0 + row) * CDIM + col] = acc2[mi][ni][r] + bn + x2f[row * 132 + col];
        }
    }
}

// ---------- Neighborhood attention v8: no-max softmax + minimal pad zeroing ----------
__global__ __launch_bounds__(256) void nat_attn8(const ushort* __restrict__ qkv,
                                                 const float* __restrict__ rpb,
                                                 ushort* __restrict__ ao) {
    __shared__ ushort katt[8704];      // union: ks[208*32]=6656 / att 4w x 16 x 136 = 8704
    __shared__ ushort vs[32 * 232];
    __shared__ float rpl[169];
    ushort* ks = katt;

    int tid = threadIdx.x, wv = tid >> 6, lane = tid & 63;
    int lr = lane & 15, kg = lane >> 4;
    int bid = blockIdx.x;
    int blk = (bid & 7) * 98 + (bid >> 3);   // bijective XCD chunking (784 = 8*98)
    int tile = blk % 49, hb2 = blk / 49;
    int head = hb2 & 3, b = hb2 >> 2;
    int r0 = (tile / 7) * 8, c0 = (tile % 7) * 8;
    int hr0 = min(max(r0 - 3, 0), HSZ - 14);
    int hc0 = min(max(c0 - 3, 0), WSZ - 14);
    int bimg = b * HSZ * WSZ;

    const ushort* qb = qkv + (size_t)(0 + head) * TOK * HD;
    const ushort* kb = qkv + (size_t)(4 + head) * TOK * HD;
    const ushort* vb = qkv + (size_t)(8 + head) * TOK * HD;

    // ---- phase 0: stage K (swizzled slots), V transposed (paired), rpb ----
    if (tid < 169) rpl[tid] = rpb[head * 169 + tid];
    for (int idx = tid; idx < 784; idx += 256) {
        int t = idx >> 2, c = idx & 3;
        int gtok = bimg + (hr0 + t / 14) * WSZ + hc0 + t % 14;
        short8 v = *(const short8*)(kb + (size_t)gtok * HD + c * 8);
        *(short8*)(ks + t * 32 + ((c ^ (t & 3)) << 3)) = v;
    }
    for (int idx = tid; idx < 392; idx += 256) {
        int pr = idx >> 2, c = idx & 3;
        int t = pr * 2;
        int gtok = bimg + (hr0 + t / 14) * WSZ + hc0 + t % 14;
        const ushort* vp = vb + (size_t)gtok * HD + c * 8;
        short8 v0 = *(const short8*)vp;
        short8 v1 = *(const short8*)(vp + HD);
        #pragma unroll
        for (int q = 0; q < 8; q++)
            *(uint*)(vs + (c * 8 + q) * 232 + t) =
                (uint)(ushort)v0[q] | ((uint)(ushort)v1[q] << 16);
    }
    for (int idx = tid; idx < 32 * 18; idx += 256)
        *(uint*)(vs + (idx / 18) * 232 + 196 + (idx % 18) * 2) = 0;
    __syncthreads();

    int i0 = r0 + 2 * wv;
    int hw0 = min(max(i0 - 3, 0), HSZ - KS);
    int dwr = hw0 - hr0;
    int tbase = dwr * 14;
    int rb = tbase & ~7;
    int rboff = tbase - rb;                  // even, in {0,2,4,6}

    int lpix = lr;
    int agp = bimg + (r0 + 2 * wv + (lpix >> 3)) * WSZ + c0 + (lpix & 7);
    short8 aq = *(const short8*)(qb + (size_t)agp * HD + kg * 8);
    f32x4 sc[7];
    #pragma unroll
    for (int tl = 0; tl < 7; tl++) {
        int t = tbase + tl * 16 + lr;
        short8 bk = *(const short8*)(ks + t * 32 + ((kg ^ (t & 3)) << 3));
        f32x4 z = {0.f, 0.f, 0.f, 0.f};
        sc[tl] = __builtin_amdgcn_mfma_f32_16x16x32_bf16(aq, bk, z, 0, 0, 0);
    }
    __syncthreads();   // all ks reads done before att overwrites the union

    // ---- zero only the 16 pad cols per row: [0,rboff) and [rboff+112,128) ----
    ushort* attw = katt + wv * 16 * 136;
    #pragma unroll
    for (int z = 0; z < 2; z++) {
        int ii = z * 64 + lane;              // 0..127 pad-uints (16 rows x 8)
        int row = ii >> 3, c2 = (ii & 7) * 2;
        int col = c2 + (c2 < rboff ? 0 : 112);
        *(uint*)(attw + row * 136 + col) = 0;
    }

    // ---- no-max softmax: e = exp(s + bias) (scores O(1) after LN; no overflow) ----
    float inv[4];
    #pragma unroll
    for (int r = 0; r < 4; r++) {
        int idx = kg * 4 + r;
        int i = r0 + 2 * wv + (idx >> 3), j = c0 + (idx & 7);
        int shh = min(max(i - 3, 0), HSZ - KS);
        int sww = min(max(j - 3, 0), WSZ - KS);
        int dih = shh - hr0, dj = sww - hc0;
        int offh = hr0 - i + 6, offw = hc0 - j + 6;
        float sum = 0.f;
        #pragma unroll
        for (int tl = 0; tl < 7; tl++) {
            int t = tbase + tl * 16 + lr;
            int thr = (unsigned)t / 14u;
            int twr = t - thr * 14;
            bool in = ((unsigned)(thr - dih) < 7u) && ((unsigned)(twr - dj) < 7u);
            int bidx = (thr + offh) * 13 + (twr + offw);
            bidx = min(max(bidx, 0), 168);
            float e = in ? __expf(sc[tl][r] + rpl[bidx]) : 0.f;
            sum += e;
            attw[idx * 136 + rboff + tl * 16 + lr] = f2b(e);
        }
        #pragma unroll
        for (int o = 8; o > 0; o >>= 1) sum += __shfl_xor(sum, o);
        inv[r] = 1.0f / sum;
    }

    // ---- PV via MFMA (4 K-steps of 32 over [rb, rb+128)) ----
    f32x4 po[2] = {};
    #pragma unroll
    for (int kst = 0; kst < 4; kst++) {
        short8 pa = *(const short8*)(attw + lr * 136 + kst * 32 + kg * 8);
        #pragma unroll
        for (int n = 0; n < 2; n++) {
            short8 vbf = *(const short8*)(vs + (n * 16 + lr) * 232 + rb + kst * 32 + kg * 8);
            po[n] = __builtin_amdgcn_mfma_f32_16x16x32_bf16(pa, vbf, po[n], 0, 0, 0);
        }
    }

    #pragma unroll
    for (int n = 0; n < 2; n++)
    #pragma unroll
    for (int rr = 0; rr < 4; rr++) {
        int idx = kg * 4 + rr;
        int gp = bimg + (r0 + 2 * wv + (idx >> 3)) * WSZ + c0 + (idx & 7);
        ao[(size_t)gp * CDIM + head * HD + n * 16 + lr] = f2b(po[n][rr] * inv[rr]);
    }
}

extern "C" void kernel_launch(void* const* d_in, const int* in_sizes, int n_in,
                              void* d_out, int out_size, void* d_ws, size_t ws_size,
                              hipStream_t stream) {
    const float* x      = (const float*)d_in[0];
    const float* n1w    = (const float*)d_in[1];
    const float* n1b    = (const float*)d_in[2];
    const float* qkv_w  = (const float*)d_in[3];
    const float* qkv_b  = (const float*)d_in[4];
    const float* rpb    = (const float*)d_in[5];
    const float* proj_w = (const float*)d_in[6];
    const float* proj_b = (const float*)d_in[7];
    const float* n2w    = (const float*)d_in[8];
    const float* n2b    = (const float*)d_in[9];
    const float* fc1_w  = (const float*)d_in[10];
    const float* fc1_b  = (const float*)d_in[11];
    const float* fc2_w  = (const float*)d_in[12];
    const float* fc2_b  = (const float*)d_in[13];
    float* out = (float*)d_out;

    ushort* wb   = (ushort*)d_ws;                        // 196608 bf16 weights
    ushort* qkvb = wb + 196608;                          // [3][4][TOK][32] bf16
    ushort* aob  = qkvb + (size_t)TOK * 384;             // TOK*128 bf16

    const ushort* w_qkv  = wb;
    const ushort* w_proj = wb + 49152;
    const ushort* w_fc1  = wb + 65536;
    const ushort* w_fc2  = wb + 131072;

    convert_w<<<192, 256, 0, stream>>>(qkv_w, proj_w, fc1_w, fc2_w, wb);
    ln1_qkv<<<TOK / 64, 512, 0, stream>>>(x, w_qkv, qkv_b, n1w, n1b, qkvb);
    nat_attn8<<<4 * NHEAD * 49, 256, 0, stream>>>(qkvb, rpb, aob);
    proj_mlp<<<TOK / 64, 512, 0, stream>>>(aob, w_proj, proj_b, x,
                                           w_fc1, fc1_b, w_fc2, fc2_b, n2w, n2b, out);
}